// Round 4
// baseline (216.854 us; speedup 1.0000x reference)
//
#include <hip/hip_runtime.h>

#define NN 8192

typedef __bf16 bf16x8 __attribute__((ext_vector_type(8)));
typedef float f32x4 __attribute__((ext_vector_type(4)));
typedef unsigned short u16x8 __attribute__((ext_vector_type(8)));

#define GLOBAL_AS __attribute__((address_space(1)))
#define LDS_AS __attribute__((address_space(3)))

__device__ __forceinline__ unsigned short f2bf(float f) {
  unsigned int u = __builtin_bit_cast(unsigned int, f);
  u += 0x7FFFu + ((u >> 16) & 1u);   // RNE
  return (unsigned short)(u >> 16);
}
__device__ __forceinline__ float bf2f(unsigned short b) {
  unsigned int u = ((unsigned int)b) << 16;
  return __builtin_bit_cast(float, u);
}

// ---------------------------------------------------------------------------
// K0: pack.  Streams adj (268 MB) ONCE at full HBM BW; emits
//   mask[row][c] : uint64, bit b = (adj[row][c*64+b] > 0)        (8 MB)
//   degp[half][row] : popcount of row half                        (64 KB)
// One wave per (row, half): 64 iters of {coalesced dword load, ballot}.
// ---------------------------------------------------------------------------
__global__ __launch_bounds__(256) void pack_kernel(
    const int* __restrict__ adj, unsigned long long* __restrict__ mask,
    float* __restrict__ degp) {
  __shared__ unsigned long long sm[4][64];
  const int lane = threadIdx.x & 63;
  const int wv = threadIdx.x >> 6;
  const int wid = (blockIdx.x << 2) + wv;
  const int row = wid >> 1, half = wid & 1;
  const int* src = adj + (size_t)row * NN + half * 4096 + lane;
  int deg = 0;
#pragma unroll
  for (int c = 0; c < 64; ++c) {
    int v = src[c * 64];
    unsigned long long m = __ballot(v > 0);
    if (lane == 0) sm[wv][c] = m;
    deg += (int)__popcll(m);
  }
  __syncthreads();
  mask[(size_t)row * 128 + half * 64 + lane] = sm[wv][lane];
  if (lane == 0) degp[half * NN + row] = (float)deg;
}

// ---------------------------------------------------------------------------
// K1: prep.  Per block: one batch b, 64 nodes.  Computes
//   Yt[(b*64+fo)][j] = bf16( x[b,j,:] @ W_neigh[:,fo] )  (transposed+swizzled)
//   Sbf[b,j,fo]      = bf16( x[b,j,:] @ W_self [:,fo] + b_self[fo] )  -> ws
// ---------------------------------------------------------------------------
__global__ __launch_bounds__(256) void prep_kernel(
    const float* __restrict__ x, const float* __restrict__ Wself,
    const float* __restrict__ bself, const float* __restrict__ Wneigh,
    unsigned short* __restrict__ Yt, unsigned short* __restrict__ Sout) {
  __shared__ __align__(16) unsigned short xa[64 * 64];    // [j][k] swizzled
  __shared__ __align__(16) unsigned short bm[128 * 64];   // [n][k]; n<64: Wneigh, n>=64: Wself
  const int t = threadIdx.x;
  const int b = blockIdx.x >> 7;
  const int j0 = (blockIdx.x & 127) << 6;

  {
    const float* Wsel = (t < 128) ? Wneigh : Wself;
    const int tt = t & 127;
    const int k = tt >> 1;
    const int c0 = (tt & 1) << 5;
    const int nbase = (t < 128) ? 0 : 64;
    const float4* src = (const float4*)(Wsel + k * 64 + c0);
#pragma unroll
    for (int q = 0; q < 8; ++q) {
      float4 v = src[q];
      int n0 = nbase + c0 + q * 4;
      int n;
      n = n0 + 0; bm[n * 64 + (k ^ ((n & 7) << 3))] = f2bf(v.x);
      n = n0 + 1; bm[n * 64 + (k ^ ((n & 7) << 3))] = f2bf(v.y);
      n = n0 + 2; bm[n * 64 + (k ^ ((n & 7) << 3))] = f2bf(v.z);
      n = n0 + 3; bm[n * 64 + (k ^ ((n & 7) << 3))] = f2bf(v.w);
    }
  }
  {
    const int j = t >> 2, q = t & 3;
    const float* xrow = x + ((size_t)b * NN + j0 + j) * 64 + q * 16;
    float4 v0 = *(const float4*)(xrow + 0);
    float4 v1 = *(const float4*)(xrow + 4);
    float4 v2 = *(const float4*)(xrow + 8);
    float4 v3 = *(const float4*)(xrow + 12);
    u16x8 p0, p1;
    p0[0] = f2bf(v0.x); p0[1] = f2bf(v0.y); p0[2] = f2bf(v0.z); p0[3] = f2bf(v0.w);
    p0[4] = f2bf(v1.x); p0[5] = f2bf(v1.y); p0[6] = f2bf(v1.z); p0[7] = f2bf(v1.w);
    p1[0] = f2bf(v2.x); p1[1] = f2bf(v2.y); p1[2] = f2bf(v2.z); p1[3] = f2bf(v2.w);
    p1[4] = f2bf(v3.x); p1[5] = f2bf(v3.y); p1[6] = f2bf(v3.z); p1[7] = f2bf(v3.w);
    const int base = q * 16;
    const int sw = (j & 7) << 3;
    *(u16x8*)&xa[j * 64 + (base ^ sw)] = p0;
    *(u16x8*)&xa[j * 64 + ((base + 8) ^ sw)] = p1;
  }
  __syncthreads();

  const int lane = t & 63, w = t >> 6;
  const int rl = lane & 15, hi = lane >> 4;
  f32x4 acc[8];
#pragma unroll
  for (int i = 0; i < 8; ++i) acc[i] = (f32x4){0.f, 0.f, 0.f, 0.f};

#pragma unroll
  for (int ks = 0; ks < 2; ++ks) {
    const int r = w * 16 + rl;
    const int kel = ks * 32 + hi * 8;
    bf16x8 af = __builtin_bit_cast(bf16x8, *(u16x8*)&xa[r * 64 + (kel ^ ((r & 7) << 3))]);
#pragma unroll
    for (int nf = 0; nf < 8; ++nf) {
      const int n = nf * 16 + rl;
      bf16x8 bv = __builtin_bit_cast(bf16x8, *(u16x8*)&bm[n * 64 + (kel ^ ((n & 7) << 3))]);
      acc[nf] = __builtin_amdgcn_mfma_f32_16x16x32_bf16(af, bv, acc[nf], 0, 0, 0);
    }
  }
#pragma unroll
  for (int nf = 0; nf < 8; ++nf) {
    if (nf < 4) {
      const int n = nf * 16 + rl;
      unsigned short* yrow = Yt + (size_t)(b * 64 + n) * NN + j0;
      const int swn = (n & 7) << 3;
#pragma unroll
      for (int r = 0; r < 4; ++r) {
        const int jj = w * 16 + hi * 4 + r;
        yrow[jj ^ swn] = f2bf(acc[nf][r]);
      }
    } else {
      const int fo = (nf - 4) * 16 + rl;
      const float bsv = bself[fo];
#pragma unroll
      for (int r = 0; r < 4; ++r) {
        const int jj = w * 16 + hi * 4 + r;
        Sout[((size_t)b * NN + j0 + jj) * 64 + fo] = f2bf(acc[nf][r] + bsv);
      }
    }
  }
}

// ---------------------------------------------------------------------------
// K2: big GEMM  C[i][n] = sum_j bit(i,j) * Yt[n][j],  n = b*64+fo.
// BM=64, BN=256, BK=64; grid = 128mb x 2nb x 2ksp = 512 = 2 blocks/CU.
// A comes from the 8 MB BITMASK (L2-resident) — zero HBM pressure in the
// K-loop; per thread one u64 load/step, expanded 16 bits -> bf16 LDS.
// Y staged via global_load_lds from pre-swizzled ws (L2-resident slice/XCD).
// Counted-vmcnt single-barrier pipeline: per iter 8 Y ops + 1 mask op,
// end-of-iter s_waitcnt vmcnt(1) keeps only the mask prefetch in flight.
// C bf16 partials (2 planes) land in d_out (combined by epiA).
// ---------------------------------------------------------------------------
__global__ __launch_bounds__(256, 2) void gemm_kernel(
    const unsigned long long* __restrict__ mask,
    const unsigned short* __restrict__ Yt, unsigned short* __restrict__ Cp) {
  __shared__ __align__(16) unsigned short aL[2][64 * 64];    //  8 KB x2
  __shared__ __align__(16) unsigned short yL[2][256 * 64];   // 32 KB x2
  const int tid = threadIdx.x;
  const int lane = tid & 63, w = tid >> 6;
  const int nid = ((blockIdx.x & 7) << 6) + (blockIdx.x >> 3);
  const int ksp = nid >> 8;
  const int nb = (nid >> 7) & 1;
  const int mb = nid & 127;
  const int i0 = mb << 6;
  const int kbase = ksp << 12;
  const int ncol0 = nb << 8;

  // A staging: thread (row ar, 16-bit group ac16)
  const int ar = tid >> 2, ac16 = tid & 3;
  const unsigned long long* mrow = mask + (size_t)(i0 + ar) * 128 + (ksp << 6);
  const int asw = (ar & 7) << 3;
  const int aw0 = ar * 64 + ((ac16 * 16) ^ asw);
  const int aw1 = ar * 64 + ((ac16 * 16 + 8) ^ asw);
  // Y staging: wave w stages local rows [w*64, w*64+64), 8 rounds of 8 rows
  const int yn = ncol0 + (w << 6) + (lane >> 3);
  const unsigned short* ysrc0 = Yt + (size_t)yn * NN + kbase + (lane & 7) * 8;

  f32x4 acc[4][4];
#pragma unroll
  for (int mf = 0; mf < 4; ++mf)
#pragma unroll
    for (int nf = 0; nf < 4; ++nf) acc[mf][nf] = (f32x4){0.f, 0.f, 0.f, 0.f};

  const int rl = lane & 15, hi = lane >> 4;
  const int fsw = (rl & 7) << 3;

#define WAIT_VM1  asm volatile("s_waitcnt vmcnt(1)" ::: "memory")
#define WAIT_LGK0 asm volatile("s_waitcnt lgkmcnt(0)" ::: "memory")
#define BARRIER   __builtin_amdgcn_s_barrier()
#define FENCE     __builtin_amdgcn_sched_barrier(0)

#define WRITEAB(buf, MV)                                                      \
  {                                                                           \
    unsigned int bits_ = (unsigned int)((MV) >> (ac16 * 16)) & 0xFFFFu;       \
    u16x8 p0_, p1_;                                                           \
    _Pragma("unroll")                                                         \
    for (int j_ = 0; j_ < 8; ++j_) {                                          \
      p0_[j_] = ((bits_ >> j_) & 1u) ? (unsigned short)0x3F80 : (unsigned short)0; \
      p1_[j_] = ((bits_ >> (8 + j_)) & 1u) ? (unsigned short)0x3F80 : (unsigned short)0; \
    }                                                                         \
    *(u16x8*)&aL[buf][aw0] = p0_;                                             \
    *(u16x8*)&aL[buf][aw1] = p1_;                                             \
  }

#define STAGEY(buf, t)                                                        \
  {                                                                           \
    _Pragma("unroll")                                                         \
    for (int rr_ = 0; rr_ < 8; ++rr_) {                                       \
      const unsigned short* g_ = ysrc0 + (size_t)rr_ * (8 * NN) + (t) * 64;   \
      __builtin_amdgcn_global_load_lds(                                       \
          (GLOBAL_AS void*)const_cast<unsigned short*>(g_),                   \
          (LDS_AS void*)&yL[buf][((w << 6) + rr_ * 8) * 64], 16, 0, 0);       \
    }                                                                         \
  }

#define COMPUTE(buf)                                                          \
  {                                                                           \
    _Pragma("unroll")                                                         \
    for (int ks_ = 0; ks_ < 2; ++ks_) {                                       \
      const int kel_ = (ks_ * 32 + hi * 8) ^ fsw;                             \
      bf16x8 af_[4], bv_[4];                                                  \
      _Pragma("unroll")                                                       \
      for (int mf_ = 0; mf_ < 4; ++mf_)                                       \
        af_[mf_] = __builtin_bit_cast(                                        \
            bf16x8, *(u16x8*)&aL[buf][(mf_ * 16 + rl) * 64 + kel_]);          \
      _Pragma("unroll")                                                       \
      for (int nf_ = 0; nf_ < 4; ++nf_)                                       \
        bv_[nf_] = __builtin_bit_cast(                                        \
            bf16x8, *(u16x8*)&yL[buf][((w << 6) + nf_ * 16 + rl) * 64 + kel_]); \
      _Pragma("unroll")                                                       \
      for (int mf_ = 0; mf_ < 4; ++mf_)                                       \
        _Pragma("unroll")                                                     \
        for (int nf_ = 0; nf_ < 4; ++nf_)                                     \
          acc[mf_][nf_] = __builtin_amdgcn_mfma_f32_16x16x32_bf16(            \
              af_[mf_], bv_[nf_], acc[mf_][nf_], 0, 0, 0);                    \
    }                                                                         \
  }

  unsigned long long mT, mA, mB;
  // ---- prologue ----  VMEM order: Y(0) x8, M[0], M[1].
  // WRITEAB's use of mT makes the compiler drain through Y(0) (vmcnt(1)).
  STAGEY(0, 0);
  FENCE;
  mT = mrow[0];
  mA = mrow[1];
  WRITEAB(0, mT);
  WAIT_VM1;            // drain Y(0)+M[0]; keep M[1]
  WAIT_LGK0;

  // ---- iters t = 0..61 (2x unrolled); iter t computes step t ----
  for (int t2 = 0; t2 < 62; t2 += 2) {
    BARRIER; FENCE;
    STAGEY(1, t2 + 1);
    FENCE;
    mB = mrow[t2 + 2];
    COMPUTE(0);
    WRITEAB(1, mA);      // A(t2+1)
    WAIT_VM1;            // drain Y(t2+1); keep M[t2+2]
    WAIT_LGK0;

    BARRIER; FENCE;
    STAGEY(0, t2 + 2);
    FENCE;
    mA = mrow[t2 + 3];
    COMPUTE(1);
    WRITEAB(0, mB);      // A(t2+2)
    WAIT_VM1;
    WAIT_LGK0;
  }
  // ---- iter 62 ----
  BARRIER; FENCE;
  STAGEY(1, 63);
  FENCE;
  mB = mrow[63];         // dummy: keeps VMEM count constant
  COMPUTE(0);
  WRITEAB(1, mA);        // A(63)
  WAIT_VM1;
  WAIT_LGK0;
  // ---- iter 63 ----
  BARRIER; FENCE;
  COMPUTE(1);

  // C partial write (bf16 plane ksp in d_out)
#pragma unroll
  for (int mf = 0; mf < 4; ++mf)
#pragma unroll
    for (int nf = 0; nf < 4; ++nf) {
      const int col = ncol0 + (w << 6) + nf * 16 + rl;
#pragma unroll
      for (int r = 0; r < 4; ++r) {
        const int i = i0 + mf * 16 + hi * 4 + r;
        Cp[((size_t)ksp * NN + i) * 512 + col] = f2bf(acc[mf][nf][r]);
      }
    }
#undef WRITEAB
#undef STAGEY
#undef COMPUTE
#undef WAIT_VM1
#undef WAIT_LGK0
#undef BARRIER
#undef FENCE
}

// ---------------------------------------------------------------------------
// K3: epiA.  F[i][col] = deg>0 ? (Cp0+Cp1)/deg + b_neigh[fo] : 0   (bf16)
// Reads Cp planes from d_out, writes F into ws (reusing the mask region).
// ---------------------------------------------------------------------------
__global__ __launch_bounds__(256) void epiA_kernel(
    const unsigned short* __restrict__ Cp, const float* __restrict__ degp,
    const float* __restrict__ bneigh, unsigned short* __restrict__ F) {
  const int idx = (blockIdx.x << 8) + threadIdx.x;   // 524288 threads
  const size_t cidx = (size_t)idx * 8;
  const int i = (int)(cidx >> 9);
  const int fo0 = (int)(cidx & 511) & 63;
  const float deg = degp[i] + degp[NN + i];
  const bool has = deg > 0.5f;
  const float r = has ? 1.0f / deg : 0.0f;
  u16x8 c0 = *(const u16x8*)&Cp[cidx];
  u16x8 c1 = *(const u16x8*)&Cp[(size_t)NN * 512 + cidx];
  float4 bn0 = *(const float4*)&bneigh[fo0];
  float4 bn1 = *(const float4*)&bneigh[fo0 + 4];
  u16x8 f;
#pragma unroll
  for (int j = 0; j < 8; ++j) {
    const float bn = (j < 4) ? ((const float*)&bn0)[j] : ((const float*)&bn1)[j - 4];
    const float v = (bf2f(c0[j]) + bf2f(c1[j])) * r + bn;
    f[j] = has ? f2bf(v) : (unsigned short)0;
  }
  *(u16x8*)&F[cidx] = f;
}

// ---------------------------------------------------------------------------
// K4: epiB.  One wave per (b,i); lane = fo.
// v = relu(S + F); LayerNorm over fo; write f32 to d_out.
// ---------------------------------------------------------------------------
__global__ __launch_bounds__(256) void epiB_kernel(
    const unsigned short* __restrict__ F, const unsigned short* __restrict__ Sbf,
    const float* __restrict__ gamma, const float* __restrict__ beta,
    float* __restrict__ out) {
  const int lane = threadIdx.x & 63;
  const int wid = (blockIdx.x << 2) + (threadIdx.x >> 6);
  const int b = wid >> 13;
  const int i = wid & (NN - 1);
  const float sv = bf2f(Sbf[((size_t)b * NN + i) * 64 + lane]);
  const float fv = bf2f(F[(size_t)i * 512 + b * 64 + lane]);
  float v = fmaxf(sv + fv, 0.0f);
  float s1 = v, s2 = v * v;
#pragma unroll
  for (int m = 1; m < 64; m <<= 1) {
    s1 += __shfl_xor(s1, m);
    s2 += __shfl_xor(s2, m);
  }
  const float mu = s1 * 0.015625f;
  const float var = s2 * 0.015625f - mu * mu;
  const float o = (v - mu) * rsqrtf(var + 1e-5f) * gamma[lane] + beta[lane];
  out[((size_t)b * NN + i) * 64 + lane] = o;
}

extern "C" void kernel_launch(void* const* d_in, const int* in_sizes, int n_in,
                              void* d_out, int out_size, void* d_ws, size_t ws_size,
                              hipStream_t stream) {
  (void)in_sizes; (void)n_in; (void)out_size; (void)ws_size;
  const float* x      = (const float*)d_in[0];
  const int*   adj    = (const int*)d_in[1];
  const float* Wself  = (const float*)d_in[2];
  const float* bself  = (const float*)d_in[3];
  const float* Wneigh = (const float*)d_in[4];
  const float* bneigh = (const float*)d_in[5];
  const float* gamma  = (const float*)d_in[6];
  const float* beta   = (const float*)d_in[7];
  char* ws = (char*)d_ws;
  // ws layout (25,231,360 B total — identical to the proven R1-R3 footprint):
  unsigned short*     Yt   = (unsigned short*)ws;                    //  8 MB
  unsigned long long* mask = (unsigned long long*)(ws + 8388608);    //  8 MB
  unsigned short*     Sbf  = (unsigned short*)(ws + 16777216);       //  8 MB
  float*              degp = (float*)(ws + 25165824);                // 64 KB
  unsigned short*     F    = (unsigned short*)(ws + 8388608);        // alias mask (dead after gemm)
  unsigned short*     Cp   = (unsigned short*)d_out;                 // 2 bf16 planes in d_out
  float*              out  = (float*)d_out;

  pack_kernel<<<dim3(4096), dim3(256), 0, stream>>>(adj, mask, degp);
  prep_kernel<<<dim3(1024), dim3(256), 0, stream>>>(x, Wself, bself, Wneigh, Yt, Sbf);
  gemm_kernel<<<dim3(512), dim3(256), 0, stream>>>(mask, Yt, Cp);
  epiA_kernel<<<dim3(2048), dim3(256), 0, stream>>>(Cp, degp, bneigh, F);
  epiB_kernel<<<dim3(16384), dim3(256), 0, stream>>>(F, Sbf, gamma, beta, out);
}